// Round 3
// baseline (195.247 us; speedup 1.0000x reference)
//
#include <hip/hip_runtime.h>
#include <math.h>

#define K_TOP 512
#define CAND_CAP 5120

struct LvlC {
  int H, lgH, HH, lgHH;
  float fs, wsc, hsc, wex, hex, pwlo, pwhi, phlo, phhi, minwh, maxwh;
};

__device__ const LvlC LVL[4] = {
  {128, 7, 16384, 14, 0.25f,    0.8f, 1.0f, 0.2f, 0.4f, 0.008f, 0.054f, 0.008f, 0.072f, 0.005f, 0.12f},
  { 64, 6,  4096, 12, 0.125f,   0.9f, 1.2f, 0.3f, 0.6f, 0.016f, 0.072f, 0.016f, 0.096f, 0.01f,  0.16f},
  { 32, 5,  1024, 10, 0.0625f,  1.0f, 1.4f, 0.4f, 0.8f, 0.024f, 0.09f,  0.024f, 0.12f,  0.015f, 0.2f },
  { 16, 4,   256,  8, 0.03125f, 1.1f, 1.6f, 0.5f, 1.0f, 0.032f, 0.108f, 0.032f, 0.144f, 0.02f,  0.24f},
};

// Decode one anchor's box (matches reference decode_level exactly, f32, no FMA contraction)
__device__ __forceinline__ void decode_box(const LvlC& L, const float* __restrict__ boxp,
                                           const float* __restrict__ ancp,
                                           int b, int idx, float imgf,
                                           float& x0, float& y0, float& x1, float& y1)
{
#pragma clang fp contract(off)
  int a   = idx >> L.lgHH;
  int rem = idx & (L.HH - 1);
  const float* bp = boxp + (size_t)((b * 3 + a) * 4) * L.HH + rem;
  float d0 = bp[0], d1 = bp[L.HH], d2 = bp[2 * L.HH], d3 = bp[3 * L.HH];
  const float* ap = ancp + (size_t)idx * 4;
  float a0 = ap[0], a1 = ap[1], a2 = ap[2], a3 = ap[3];
  float aw  = (a2 - a0) / imgf;
  float ah  = (a3 - a1) / imgf;
  float acx = (a0 + a2) * 0.5f / imgf;
  float acy = (a1 + a3) * 0.5f / imgf;
  float dx = fminf(fmaxf(d0 * 0.2f, -1.f), 1.f) * L.fs * aw;
  float dy = fminf(fmaxf(d1 * 0.2f, -1.f), 1.f) * L.fs * ah;
  float cx = fminf(fmaxf(acx + dx, 0.f), 1.f);
  float cy = fminf(fmaxf(acy + dy, 0.f), 1.f);
  float dw = fminf(fmaxf(d2 * 0.2f, -2.f), 2.f);
  float dh = fminf(fmaxf(d3 * 0.2f, -2.f), 2.f);
  float pw = fminf(fmaxf(aw * L.wsc * expf(dw * L.wex), L.pwlo), L.pwhi);
  float ph = fminf(fmaxf(ah * L.hsc * expf(dh * L.hex), L.phlo), L.phhi);
  x0 = fminf(fmaxf(cx - 0.5f * pw, 0.f), 1.f);
  y0 = fminf(fmaxf(cy - 0.5f * ph, 0.f), 1.f);
  x1 = fminf(fmaxf(cx + 0.5f * pw, 0.f), 1.f);
  y1 = fminf(fmaxf(cy + 0.5f * ph, 0.f), 1.f);
}

__device__ __forceinline__ void seg_map(int blk, int& b, int& l, int& base, int& iblk)
{
  b = blk / 255;                 // 255 blocks per batch (65280/256)
  int rb = blk - b * 255;
  if (rb < 192)      { l = 0; iblk = rb;       base = 0;     }
  else if (rb < 240) { l = 1; iblk = rb - 192; base = 49152; }
  else if (rb < 252) { l = 2; iblk = rb - 240; base = 61440; }
  else               { l = 3; iblk = rb - 252; base = 64512; }
}

// ---------------- Kernel 1: decode all anchors -> 64-bit keys + 12-bit global hist ----------------
// key = [ ~flip(sort_key) :32 | idx:16 | label:8 | valid:1 ]  (ascending u64 == top_k order)
__global__ __launch_bounds__(256) void decode_kernel(
    const float* __restrict__ cls0, const float* __restrict__ box0, const float* __restrict__ anc0,
    const float* __restrict__ cls1, const float* __restrict__ box1, const float* __restrict__ anc1,
    const float* __restrict__ cls2, const float* __restrict__ box2, const float* __restrict__ anc2,
    const float* __restrict__ cls3, const float* __restrict__ box3, const float* __restrict__ anc3,
    const int* __restrict__ imgp, unsigned long long* __restrict__ keys,
    unsigned* __restrict__ ghist)
{
  __shared__ unsigned lhist[4096];
  int tid = (int)threadIdx.x;
#pragma unroll
  for (int v = tid; v < 4096; v += 256) lhist[v] = 0u;

  int b, l, base, iblk;
  seg_map((int)blockIdx.x, b, l, base, iblk);
  int i = iblk * 256 + tid;

  const float *cls, *boxp, *ancp;
  switch (l) {
    case 0:  cls = cls0; boxp = box0; ancp = anc0; break;
    case 1:  cls = cls1; boxp = box1; ancp = anc1; break;
    case 2:  cls = cls2; boxp = box2; ancp = anc2; break;
    default: cls = cls3; boxp = box3; ancp = anc3; break;
  }
  LvlC L = LVL[l];
  float imgf = (float)(*imgp);

  int a   = i >> L.lgHH;
  int rem = i & (L.HH - 1);
  const float* cp = cls + (size_t)((b * 3 + a) * 3) * L.HH + rem;
  float c0 = cp[0], c1 = cp[L.HH], c2 = cp[2 * L.HH];
  float m = c0; int mc = 0;
  if (c1 > m) { m = c1; mc = 1; }
  if (c2 > m) { m = c2; mc = 2; }
  float ms = 1.f / (1.f + expf(-m));   // max of sigmoids == sigmoid of max logit

  float x0, y0, x1, y1;
  decode_box(L, boxp, ancp, b, i, imgf, x0, y0, x1, y1);
  float w = x1 - x0, h = y1 - y0;
  bool valid = (ms > 0.15f) && (w > L.minwh) && (h > L.minwh) && (w < L.maxwh) && (h < L.maxwh);

  float sk = valid ? ms : -1.0f;
  unsigned u = __float_as_uint(sk);
  unsigned ascu  = (u & 0x80000000u) ? ~u : (u | 0x80000000u); // ascending-float -> ascending-uint
  unsigned descu = ~ascu;                                      // descending-float -> ascending-uint
  unsigned long long key = ((unsigned long long)descu << 32)
                         | ((unsigned long long)(unsigned)i << 16)
                         | ((unsigned)mc << 8) | (valid ? 1u : 0u);
  keys[(size_t)b * 65280 + base + i] = key;

  __syncthreads();
  atomicAdd(&lhist[(unsigned)(key >> 52)], 1u);
  __syncthreads();
  unsigned* gh = ghist + (b * 4 + l) * 4096;
#pragma unroll
  for (int v = tid; v < 4096; v += 256) {
    unsigned c = lhist[v];
    if (c) atomicAdd(&gh[v], c);
  }
}

// ---------------- Kernel 2: per-segment winning 12-bit digit + below count ----------------
__global__ __launch_bounds__(1024) void thresh_kernel(const unsigned* __restrict__ ghist,
                                                      unsigned* __restrict__ segInfo)
{
  __shared__ unsigned waveSum[16];
  int seg = (int)blockIdx.x;
  int tid = (int)threadIdx.x;
  int wid = tid >> 6, lane = tid & 63;
  const unsigned* h = ghist + seg * 4096;
  unsigned v0 = h[tid * 4], v1 = h[tid * 4 + 1], v2 = h[tid * 4 + 2], v3 = h[tid * 4 + 3];
  unsigned s = v0 + v1 + v2 + v3;
  unsigned incl = s;
  for (int off = 1; off < 64; off <<= 1) {
    unsigned n = __shfl_up(incl, off);
    if (lane >= off) incl += n;
  }
  if (lane == 63) waveSum[wid] = incl;
  __syncthreads();
  unsigned add = 0;
  for (int w2 = 0; w2 < wid; ++w2) add += waveSum[w2];
  unsigned run = incl - s + add;   // exclusive prefix of this thread's 4 bins
  unsigned bins[4] = {v0, v1, v2, v3};
#pragma unroll
  for (int j = 0; j < 4; ++j) {
    unsigned c = bins[j];
    if (run < K_TOP && run + c >= K_TOP) {
      segInfo[seg * 2]     = (unsigned)(tid * 4 + j);  // winning 12-bit digit
      segInfo[seg * 2 + 1] = run;                      // exact strictly-below count
    }
    run += c;
  }
}

// ---------------- Kernel 3: parallel compaction of candidates (single full-N pass) ----------------
__global__ __launch_bounds__(256) void compact_kernel(
    const unsigned long long* __restrict__ keys,
    const unsigned* __restrict__ segInfo,
    unsigned long long* __restrict__ cand, unsigned* __restrict__ candCnt)
{
  int b, l, base, iblk;
  seg_map((int)blockIdx.x, b, l, base, iblk);
  int tid = (int)threadIdx.x;
  int i = iblk * 256 + tid;
  int seg = b * 4 + l;
  unsigned long long key = keys[(size_t)b * 65280 + base + i];
  unsigned win = segInfo[seg * 2];
  bool take = ((unsigned)(key >> 52)) <= win;

  int lane = tid & 63;
  unsigned long long mask = __ballot(take);
  int tot = __popcll(mask);
  unsigned bp = 0;
  if (lane == 0 && tot) bp = atomicAdd(&candCnt[seg], (unsigned)tot);
  bp = __shfl(bp, 0);
  if (take) {
    unsigned slot = bp + (unsigned)__popcll(mask & ((1ull << lane) - 1ull));
    if (slot < CAND_CAP) cand[(size_t)seg * CAND_CAP + slot] = key;
  }
}

// ---------------- Kernel 4: per-segment exact top-512 over candidates + decode boxes ----------------
__global__ __launch_bounds__(512) void final_kernel(
    const unsigned long long* __restrict__ keys,
    const unsigned long long* __restrict__ cand,
    const unsigned* __restrict__ candCnt, const unsigned* __restrict__ segInfo,
    const float* __restrict__ box0, const float* __restrict__ anc0,
    const float* __restrict__ box1, const float* __restrict__ anc1,
    const float* __restrict__ box2, const float* __restrict__ anc2,
    const float* __restrict__ box3, const float* __restrict__ anc3,
    const int* __restrict__ imgp,
    float* __restrict__ boxesWS, float* __restrict__ scoresWS,
    int* __restrict__ labelsWS, unsigned* __restrict__ validWS)
{
  __shared__ unsigned long long scand[CAND_CAP];  // 40 KB
  __shared__ unsigned long long skey[K_TOP];      // 4 KB
  __shared__ unsigned hist[8][256];               // 8 KB
  __shared__ unsigned histT[256];
  __shared__ unsigned waveSum[4];
  __shared__ unsigned long long sh_prefix;
  __shared__ unsigned sh_below, sh_cnt;

  int seg = (int)blockIdx.x;
  int b = seg >> 2, l = seg & 3;
  const int nArr[4]    = {49152, 12288, 3072, 768};
  const int baseArr[4] = {0, 49152, 61440, 64512};
  int N = nArr[l];
  const unsigned long long* kp = keys + (size_t)b * 65280 + baseArr[l];
  int tid = (int)threadIdx.x;
  const int nt = 512;
  int wid = tid >> 6, lane = tid & 63;

  unsigned cnt = candCnt[seg];
  unsigned win = segInfo[seg * 2];
  unsigned below0 = segInfo[seg * 2 + 1];
  bool useCand = (cnt <= CAND_CAP);
  int M = useCand ? (int)cnt : N;
  const unsigned long long* cp = cand + (size_t)seg * CAND_CAP;

  if (useCand)
    for (int t = tid; t < M; t += nt) scand[t] = cp[t];
  if (tid == 0) {
    sh_prefix = (unsigned long long)win << 52;
    sh_below = below0;
    sh_cnt = 0u;
  }
  __syncthreads();

  unsigned long long hiMask = 0xFFFull << 52;
  for (int r = 0; r < 5; ++r) {
    int shift = 44 - 8 * r;
    for (int v = tid; v < 8 * 256; v += nt) ((unsigned*)hist)[v] = 0u;
    __syncthreads();
    unsigned long long pref = sh_prefix;
    unsigned below = sh_below;
    for (int t = tid; t < M; t += nt) {
      unsigned long long k = useCand ? scand[t] : kp[t];
      if ((k & hiMask) == pref)
        atomicAdd(&hist[wid][(unsigned)((k >> shift) & 0xFF)], 1u);
    }
    __syncthreads();
    if (tid < 256) {
      unsigned s = 0;
#pragma unroll
      for (int w2 = 0; w2 < 8; ++w2) s += hist[w2][tid];
      histT[tid] = s;
    }
    __syncthreads();
    unsigned v = (tid < 256) ? histT[tid] : 0u;
    unsigned incl = v;
    for (int off = 1; off < 64; off <<= 1) {
      unsigned n = __shfl_up(incl, off);
      if (lane >= off) incl += n;
    }
    if (lane == 63 && wid < 4) waveSum[wid] = incl;
    __syncthreads();
    if (tid < 256) {
      unsigned add = 0;
      for (int w2 = 0; w2 < wid; ++w2) add += waveSum[w2];
      unsigned inclT = incl + add;
      unsigned exclT = inclT - v;
      if (below + exclT < K_TOP && below + inclT >= K_TOP) {
        sh_below = below + exclT;
        sh_prefix = pref | ((unsigned long long)(unsigned)tid << shift);
      }
    }
    __syncthreads();
    hiMask |= 0xFFull << shift;
  }
  unsigned long long kth = sh_prefix | 0xFFFull;

  // collect: exactly 512 keys satisfy key <= kth (top-48 bits unique per segment)
  for (int t = tid; t < M; t += nt) {
    unsigned long long k = useCand ? scand[t] : kp[t];
    if (k <= kth) { unsigned p = atomicAdd(&sh_cnt, 1u); skey[p] = k; }
  }
  __syncthreads();

  // bitonic sort 512 ascending
  for (int kk = 2; kk <= K_TOP; kk <<= 1) {
    for (int j = kk >> 1; j > 0; j >>= 1) {
      int ixj = tid ^ j;
      if (ixj > tid) {
        bool up = ((tid & kk) == 0);
        unsigned long long A = skey[tid], B = skey[ixj];
        if ((A > B) == up) { skey[tid] = B; skey[ixj] = A; }
      }
      __syncthreads();
    }
  }

  // epilogue: decode the 512 selected boxes to ws
  {
    unsigned long long key = skey[tid];
    const float *boxp, *ancp;
    switch (l) {
      case 0:  boxp = box0; ancp = anc0; break;
      case 1:  boxp = box1; ancp = anc1; break;
      case 2:  boxp = box2; ancp = anc2; break;
      default: boxp = box3; ancp = anc3; break;
    }
    LvlC L = LVL[l];
    float imgf = (float)(*imgp);
    int idx = (int)((key >> 16) & 0xFFFFull);
    unsigned descu = (unsigned)(key >> 32);
    unsigned ascu  = ~descu;
    unsigned u = (ascu & 0x80000000u) ? (ascu & 0x7FFFFFFFu) : ~ascu;
    float x0, y0, x1, y1;
    decode_box(L, boxp, ancp, b, idx, imgf, x0, y0, x1, y1);
    int o = seg * K_TOP + tid;
    float4 bb; bb.x = x0; bb.y = y0; bb.z = x1; bb.w = y1;
    reinterpret_cast<float4*>(boxesWS)[o] = bb;
    scoresWS[o] = __uint_as_float(u);
    labelsWS[o] = (int)((key >> 8) & 0xFFull);
    validWS[o]  = (unsigned)(key & 1ull);
  }
}

// ---------------- Kernel 5: pairwise IoU>T suppression bitmasks (massively parallel) ----------------
__global__ __launch_bounds__(256) void mask_kernel(
    const float* __restrict__ boxesWS, unsigned long long* __restrict__ masks)
{
#pragma clang fp contract(off)
  int blk = (int)blockIdx.x;          // 512 blocks; 32 per segment
  int seg = blk >> 5;
  int wid = (int)threadIdx.x >> 6;    // 4 waves
  int lane = (int)threadIdx.x & 63;
  int waveInSeg = (blk & 31) * 4 + wid;   // 0..127, 4 rows each
  const float4* bb = reinterpret_cast<const float4*>(boxesWS) + seg * K_TOP;

  float4 bj[8]; float aj[8];
#pragma unroll
  for (int c = 0; c < 8; ++c) {
    bj[c] = bb[c * 64 + lane];
    aj[c] = (bj[c].z - bj[c].x) * (bj[c].w - bj[c].y);
  }
#pragma unroll
  for (int rr = 0; rr < 4; ++rr) {
    int r = waveInSeg * 4 + rr;
    float4 br = bb[r];
    float ar_ = (br.z - br.x) * (br.w - br.y);
    unsigned long long* mrow = masks + ((size_t)seg * K_TOP + r) * 8;
#pragma unroll
    for (int c = 0; c < 8; ++c) {
      float ltx = fmaxf(br.x, bj[c].x), lty = fmaxf(br.y, bj[c].y);
      float rbx = fminf(br.z, bj[c].z), rby = fminf(br.w, bj[c].w);
      float ww = fmaxf(rbx - ltx, 0.f), hh = fmaxf(rby - lty, 0.f);
      float inter = ww * hh;
      float iou = inter / (ar_ + aj[c] - inter + 1e-9f);
      unsigned long long bal = __ballot(iou > 0.5f);
      if (lane == 0) mrow[c] = bal;
    }
  }
}

// ---------------- Kernel 6: serial greedy scan over bitmasks + output write ----------------
__global__ __launch_bounds__(512) void scan_kernel(
    const unsigned long long* __restrict__ masks,
    const float* __restrict__ boxesWS, const float* __restrict__ scoresWS,
    const int* __restrict__ labelsWS, const unsigned* __restrict__ validWS,
    float* __restrict__ out)
{
  __shared__ unsigned long long sMask[K_TOP * 8];
  __shared__ unsigned sValid[K_TOP];
  __shared__ unsigned long long keepWords[8];

  int seg = (int)blockIdx.x;
  int tid = (int)threadIdx.x;
  const unsigned long long* mp = masks + (size_t)seg * K_TOP * 8;
#pragma unroll
  for (int k2 = 0; k2 < 8; ++k2) sMask[tid * 8 + k2] = mp[tid * 8 + k2];
  sValid[tid] = validWS[seg * K_TOP + tid];
  __syncthreads();

  if (tid < 8) {
    // lanes 0..7 each own one 64-bit word of the kept bitset
    unsigned long long kept = 0ull;
    for (int i = 0; i < K_TOP; ++i) {
      unsigned long long row = sMask[i * 8 + tid];
      unsigned long long confl = __ballot((row & kept) != 0ull);
      bool ok = (sValid[i] != 0u) && (confl == 0ull);
      kept |= (ok && (tid == (i >> 6))) ? (1ull << (i & 63)) : 0ull;
    }
    keepWords[tid] = kept;
  }
  __syncthreads();

  int o = seg * K_TOP + tid;
  bool keep = (keepWords[tid >> 6] >> (tid & 63)) & 1ull;
  float4 bx = reinterpret_cast<const float4*>(boxesWS)[o];
  float4 ob;
  ob.x = keep ? bx.x : 0.f;
  ob.y = keep ? bx.y : 0.f;
  ob.z = keep ? bx.z : 0.f;
  ob.w = keep ? bx.w : 0.f;
  reinterpret_cast<float4*>(out)[o] = ob;                   // boxes:  [0,      32768)
  out[32768 + o] = keep ? scoresWS[o] : 0.f;                // scores: [32768,  40960)
  out[40960 + o] = keep ? (float)(labelsWS[o] + 1) : 0.f;   // labels: [40960,  49152)
  out[49152 + o] = keep ? 1.f : 0.f;                        // keep:   [49152,  57344)
}

extern "C" void kernel_launch(void* const* d_in, const int* in_sizes, int n_in,
                              void* d_out, int out_size, void* d_ws, size_t ws_size,
                              hipStream_t stream)
{
  const float* cls0 = (const float*)d_in[0];
  const float* box0 = (const float*)d_in[1];
  const float* anc0 = (const float*)d_in[2];
  const float* cls1 = (const float*)d_in[3];
  const float* box1 = (const float*)d_in[4];
  const float* anc1 = (const float*)d_in[5];
  const float* cls2 = (const float*)d_in[6];
  const float* box2 = (const float*)d_in[7];
  const float* anc2 = (const float*)d_in[8];
  const float* cls3 = (const float*)d_in[9];
  const float* box3 = (const float*)d_in[10];
  const float* anc3 = (const float*)d_in[11];
  const int*   imgp = (const int*)d_in[12];

  // ws layout (bytes):
  char* ws = (char*)d_ws;
  unsigned long long* keys    = (unsigned long long*)(ws + 0);         // 261120*8 = 2,088,960
  unsigned long long* masks   = (unsigned long long*)(ws + 2088960);   // 524,288
  float*              boxesWS = (float*)(ws + 2613248);                // 131,072
  float*              scoresWS= (float*)(ws + 2744320);                // 32,768
  int*                labelsWS= (int*)(ws + 2777088);                  // 32,768
  unsigned*           validWS = (unsigned*)(ws + 2809856);             // 32,768
  unsigned*           ghist   = (unsigned*)(ws + 2842624);             // 16*4096*4 = 262,144
  unsigned*           segInfo = (unsigned*)(ws + 3104768);             // 128
  unsigned*           candCnt = (unsigned*)(ws + 3104896);             // 64
  unsigned long long* cand    = (unsigned long long*)(ws + 3104960);   // 16*5120*8 = 655,360
  float* out = (float*)d_out;

  // zero ghist + segInfo + candCnt in one contiguous memset
  hipMemsetAsync(ghist, 0, 262144 + 128 + 64, stream);

  decode_kernel<<<1020, 256, 0, stream>>>(cls0, box0, anc0, cls1, box1, anc1,
                                          cls2, box2, anc2, cls3, box3, anc3,
                                          imgp, keys, ghist);
  thresh_kernel<<<16, 1024, 0, stream>>>(ghist, segInfo);
  compact_kernel<<<1020, 256, 0, stream>>>(keys, segInfo, cand, candCnt);
  final_kernel<<<16, 512, 0, stream>>>(keys, cand, candCnt, segInfo,
                                       box0, anc0, box1, anc1, box2, anc2, box3, anc3,
                                       imgp, boxesWS, scoresWS, labelsWS, validWS);
  mask_kernel<<<512, 256, 0, stream>>>(boxesWS, masks);
  scan_kernel<<<16, 512, 0, stream>>>(masks, boxesWS, scoresWS, labelsWS, validWS, out);
}

// Round 4
// 154.029 us; speedup vs baseline: 1.2676x; 1.2676x over previous
//
#include <hip/hip_runtime.h>
#include <math.h>

#define K_TOP 512
#define CAND_CAP 5120

struct LvlC {
  int H, lgH, HH, lgHH;
  float fs, wsc, hsc, wex, hex, pwlo, pwhi, phlo, phhi, minwh, maxwh;
};

__device__ const LvlC LVL[4] = {
  {128, 7, 16384, 14, 0.25f,    0.8f, 1.0f, 0.2f, 0.4f, 0.008f, 0.054f, 0.008f, 0.072f, 0.005f, 0.12f},
  { 64, 6,  4096, 12, 0.125f,   0.9f, 1.2f, 0.3f, 0.6f, 0.016f, 0.072f, 0.016f, 0.096f, 0.01f,  0.16f},
  { 32, 5,  1024, 10, 0.0625f,  1.0f, 1.4f, 0.4f, 0.8f, 0.024f, 0.09f,  0.024f, 0.12f,  0.015f, 0.2f },
  { 16, 4,   256,  8, 0.03125f, 1.1f, 1.6f, 0.5f, 1.0f, 0.032f, 0.108f, 0.032f, 0.144f, 0.02f,  0.24f},
};

// Decode one anchor's box (matches reference decode_level exactly, f32, no FMA contraction)
__device__ __forceinline__ void decode_box(const LvlC& L, const float* __restrict__ boxp,
                                           const float* __restrict__ ancp,
                                           int b, int idx, float imgf,
                                           float& x0, float& y0, float& x1, float& y1)
{
#pragma clang fp contract(off)
  int a   = idx >> L.lgHH;
  int rem = idx & (L.HH - 1);
  const float* bp = boxp + (size_t)((b * 3 + a) * 4) * L.HH + rem;
  float d0 = bp[0], d1 = bp[L.HH], d2 = bp[2 * L.HH], d3 = bp[3 * L.HH];
  float4 av = reinterpret_cast<const float4*>(ancp)[idx];
  float a0 = av.x, a1 = av.y, a2 = av.z, a3 = av.w;
  float aw  = (a2 - a0) / imgf;
  float ah  = (a3 - a1) / imgf;
  float acx = (a0 + a2) * 0.5f / imgf;
  float acy = (a1 + a3) * 0.5f / imgf;
  float dx = fminf(fmaxf(d0 * 0.2f, -1.f), 1.f) * L.fs * aw;
  float dy = fminf(fmaxf(d1 * 0.2f, -1.f), 1.f) * L.fs * ah;
  float cx = fminf(fmaxf(acx + dx, 0.f), 1.f);
  float cy = fminf(fmaxf(acy + dy, 0.f), 1.f);
  float dw = fminf(fmaxf(d2 * 0.2f, -2.f), 2.f);
  float dh = fminf(fmaxf(d3 * 0.2f, -2.f), 2.f);
  float pw = fminf(fmaxf(aw * L.wsc * expf(dw * L.wex), L.pwlo), L.pwhi);
  float ph = fminf(fmaxf(ah * L.hsc * expf(dh * L.hex), L.phlo), L.phhi);
  x0 = fminf(fmaxf(cx - 0.5f * pw, 0.f), 1.f);
  y0 = fminf(fmaxf(cy - 0.5f * ph, 0.f), 1.f);
  x1 = fminf(fmaxf(cx + 0.5f * pw, 0.f), 1.f);
  y1 = fminf(fmaxf(cy + 0.5f * ph, 0.f), 1.f);
}

__device__ __forceinline__ void seg_map(int blk, int& b, int& l, int& base, int& iblk)
{
  b = blk / 255;                 // 255 blocks per batch (65280/256)
  int rb = blk - b * 255;
  if (rb < 192)      { l = 0; iblk = rb;       base = 0;     }
  else if (rb < 240) { l = 1; iblk = rb - 192; base = 49152; }
  else if (rb < 252) { l = 2; iblk = rb - 240; base = 61440; }
  else               { l = 3; iblk = rb - 252; base = 64512; }
}

// ---------------- Kernel 1: decode all anchors -> 64-bit keys + 12-bit global hist ----------------
// key = [ ~flip(sort_key) :32 | idx:16 | label:8 | valid:1 ]  (ascending u64 == top_k order)
__global__ __launch_bounds__(256) void decode_kernel(
    const float* __restrict__ cls0, const float* __restrict__ box0, const float* __restrict__ anc0,
    const float* __restrict__ cls1, const float* __restrict__ box1, const float* __restrict__ anc1,
    const float* __restrict__ cls2, const float* __restrict__ box2, const float* __restrict__ anc2,
    const float* __restrict__ cls3, const float* __restrict__ box3, const float* __restrict__ anc3,
    const int* __restrict__ imgp, unsigned long long* __restrict__ keys,
    unsigned* __restrict__ ghist)
{
  __shared__ unsigned lhist[4096];
  int tid = (int)threadIdx.x;
#pragma unroll
  for (int v = tid; v < 4096; v += 256) lhist[v] = 0u;

  int b, l, base, iblk;
  seg_map((int)blockIdx.x, b, l, base, iblk);
  int i = iblk * 256 + tid;

  const float *cls, *boxp, *ancp;
  switch (l) {
    case 0:  cls = cls0; boxp = box0; ancp = anc0; break;
    case 1:  cls = cls1; boxp = box1; ancp = anc1; break;
    case 2:  cls = cls2; boxp = box2; ancp = anc2; break;
    default: cls = cls3; boxp = box3; ancp = anc3; break;
  }
  LvlC L = LVL[l];
  float imgf = (float)(*imgp);

  int a   = i >> L.lgHH;
  int rem = i & (L.HH - 1);
  const float* cp = cls + (size_t)((b * 3 + a) * 3) * L.HH + rem;
  float c0 = cp[0], c1 = cp[L.HH], c2 = cp[2 * L.HH];
  float m = c0; int mc = 0;
  if (c1 > m) { m = c1; mc = 1; }
  if (c2 > m) { m = c2; mc = 2; }
  float ms = 1.f / (1.f + expf(-m));   // max of sigmoids == sigmoid of max logit

  float x0, y0, x1, y1;
  decode_box(L, boxp, ancp, b, i, imgf, x0, y0, x1, y1);
  float w = x1 - x0, h = y1 - y0;
  bool valid = (ms > 0.15f) && (w > L.minwh) && (h > L.minwh) && (w < L.maxwh) && (h < L.maxwh);

  float sk = valid ? ms : -1.0f;
  unsigned u = __float_as_uint(sk);
  unsigned ascu  = (u & 0x80000000u) ? ~u : (u | 0x80000000u); // ascending-float -> ascending-uint
  unsigned descu = ~ascu;                                      // descending-float -> ascending-uint
  unsigned long long key = ((unsigned long long)descu << 32)
                         | ((unsigned long long)(unsigned)i << 16)
                         | ((unsigned)mc << 8) | (valid ? 1u : 0u);
  keys[(size_t)b * 65280 + base + i] = key;

  __syncthreads();
  atomicAdd(&lhist[(unsigned)(key >> 52)], 1u);
  __syncthreads();
  unsigned* gh = ghist + (b * 4 + l) * 4096;
#pragma unroll
  for (int v = tid; v < 4096; v += 256) {
    unsigned c = lhist[v];
    if (c) atomicAdd(&gh[v], c);
  }
}

// ---------------- Kernel 2: per-segment winning 12-bit digit + below count ----------------
__global__ __launch_bounds__(1024) void thresh_kernel(const unsigned* __restrict__ ghist,
                                                      unsigned* __restrict__ segInfo)
{
  __shared__ unsigned waveSum[16];
  int seg = (int)blockIdx.x;
  int tid = (int)threadIdx.x;
  int wid = tid >> 6, lane = tid & 63;
  const unsigned* h = ghist + seg * 4096;
  unsigned v0 = h[tid * 4], v1 = h[tid * 4 + 1], v2 = h[tid * 4 + 2], v3 = h[tid * 4 + 3];
  unsigned s = v0 + v1 + v2 + v3;
  unsigned incl = s;
  for (int off = 1; off < 64; off <<= 1) {
    unsigned n = __shfl_up(incl, off);
    if (lane >= off) incl += n;
  }
  if (lane == 63) waveSum[wid] = incl;
  __syncthreads();
  unsigned add = 0;
  for (int w2 = 0; w2 < wid; ++w2) add += waveSum[w2];
  unsigned run = incl - s + add;   // exclusive prefix of this thread's 4 bins
  unsigned bins[4] = {v0, v1, v2, v3};
#pragma unroll
  for (int j = 0; j < 4; ++j) {
    unsigned c = bins[j];
    if (run < K_TOP && run + c >= K_TOP) {
      segInfo[seg * 2]     = (unsigned)(tid * 4 + j);  // winning 12-bit digit
      segInfo[seg * 2 + 1] = run;                      // exact strictly-below count
    }
    run += c;
  }
}

// ---------------- Kernel 3: parallel compaction (one padded global atomic per block) ----------------
__global__ __launch_bounds__(256) void compact_kernel(
    const unsigned long long* __restrict__ keys,
    const unsigned* __restrict__ segInfo,
    unsigned long long* __restrict__ cand, unsigned* __restrict__ candCnt)
{
  __shared__ unsigned wcnt[4];
  __shared__ unsigned blockBase;
  int b, l, base, iblk;
  seg_map((int)blockIdx.x, b, l, base, iblk);
  int tid = (int)threadIdx.x;
  int wid = tid >> 6, lane = tid & 63;
  int i = iblk * 256 + tid;
  int seg = b * 4 + l;
  unsigned long long key = keys[(size_t)b * 65280 + base + i];
  unsigned win = segInfo[seg * 2];
  bool take = ((unsigned)(key >> 52)) <= win;

  unsigned long long m = __ballot(take);
  if (lane == 0) wcnt[wid] = (unsigned)__popcll(m);
  __syncthreads();
  if (tid == 0) {
    unsigned s = wcnt[0] + wcnt[1] + wcnt[2] + wcnt[3];
    blockBase = s ? atomicAdd(&candCnt[seg * 32], s) : 0u;   // counters padded 128B apart
  }
  __syncthreads();
  if (take) {
    unsigned off = blockBase;
    for (int w2 = 0; w2 < wid; ++w2) off += wcnt[w2];
    off += (unsigned)__popcll(m & ((1ull << lane) - 1ull));
    if (off < CAND_CAP) cand[(size_t)seg * CAND_CAP + off] = key;
  }
}

// ---------------- Kernel 4: per-segment exact top-512 over candidates + decode boxes ----------------
__global__ __launch_bounds__(512) void final_kernel(
    const unsigned long long* __restrict__ keys,
    const unsigned long long* __restrict__ cand,
    const unsigned* __restrict__ candCnt, const unsigned* __restrict__ segInfo,
    const float* __restrict__ box0, const float* __restrict__ anc0,
    const float* __restrict__ box1, const float* __restrict__ anc1,
    const float* __restrict__ box2, const float* __restrict__ anc2,
    const float* __restrict__ box3, const float* __restrict__ anc3,
    const int* __restrict__ imgp,
    float* __restrict__ boxesWS, float* __restrict__ scoresWS,
    int* __restrict__ labelsWS, unsigned* __restrict__ validWS)
{
  __shared__ unsigned long long scand[CAND_CAP];  // 40 KB
  __shared__ unsigned long long skey[K_TOP];      // 4 KB
  __shared__ unsigned hist[8][256];               // 8 KB
  __shared__ unsigned histT[256];
  __shared__ unsigned waveSum[4];
  __shared__ unsigned long long sh_prefix;
  __shared__ unsigned sh_below, sh_cnt;

  int seg = (int)blockIdx.x;
  int b = seg >> 2, l = seg & 3;
  const int nArr[4]    = {49152, 12288, 3072, 768};
  const int baseArr[4] = {0, 49152, 61440, 64512};
  int N = nArr[l];
  const unsigned long long* kp = keys + (size_t)b * 65280 + baseArr[l];
  int tid = (int)threadIdx.x;
  const int nt = 512;
  int wid = tid >> 6, lane = tid & 63;

  unsigned cnt = candCnt[seg * 32];
  unsigned win = segInfo[seg * 2];
  unsigned below0 = segInfo[seg * 2 + 1];
  bool useCand = (cnt <= CAND_CAP);
  int M = useCand ? (int)cnt : N;
  const unsigned long long* cp = cand + (size_t)seg * CAND_CAP;

  if (useCand)
    for (int t = tid; t < M; t += nt) scand[t] = cp[t];
  if (tid == 0) {
    sh_prefix = (unsigned long long)win << 52;
    sh_below = below0;
    sh_cnt = 0u;
  }
  __syncthreads();

  unsigned long long hiMask = 0xFFFull << 52;
  for (int r = 0; r < 5; ++r) {
    int shift = 44 - 8 * r;
    for (int v = tid; v < 8 * 256; v += nt) ((unsigned*)hist)[v] = 0u;
    __syncthreads();
    unsigned long long pref = sh_prefix;
    unsigned below = sh_below;
    for (int t = tid; t < M; t += nt) {
      unsigned long long k = useCand ? scand[t] : kp[t];
      if ((k & hiMask) == pref)
        atomicAdd(&hist[wid][(unsigned)((k >> shift) & 0xFF)], 1u);
    }
    __syncthreads();
    if (tid < 256) {
      unsigned s = 0;
#pragma unroll
      for (int w2 = 0; w2 < 8; ++w2) s += hist[w2][tid];
      histT[tid] = s;
    }
    __syncthreads();
    unsigned v = (tid < 256) ? histT[tid] : 0u;
    unsigned incl = v;
    for (int off = 1; off < 64; off <<= 1) {
      unsigned n = __shfl_up(incl, off);
      if (lane >= off) incl += n;
    }
    if (lane == 63 && wid < 4) waveSum[wid] = incl;
    __syncthreads();
    if (tid < 256) {
      unsigned add = 0;
      for (int w2 = 0; w2 < wid; ++w2) add += waveSum[w2];
      unsigned inclT = incl + add;
      unsigned exclT = inclT - v;
      if (below + exclT < K_TOP && below + inclT >= K_TOP) {
        sh_below = below + exclT;
        sh_prefix = pref | ((unsigned long long)(unsigned)tid << shift);
      }
    }
    __syncthreads();
    hiMask |= 0xFFull << shift;
  }
  unsigned long long kth = sh_prefix | 0xFFFull;

  // collect (ballot-aggregated): exactly 512 keys satisfy key <= kth
  for (int t = tid; t < M; t += nt) {
    unsigned long long k = useCand ? scand[t] : kp[t];
    bool take = (k <= kth);
    unsigned long long bm = __ballot(take);
    unsigned bp = 0;
    if (lane == 0 && bm) bp = atomicAdd(&sh_cnt, (unsigned)__popcll(bm));
    bp = __shfl(bp, 0);
    if (take) skey[bp + (unsigned)__popcll(bm & ((1ull << lane) - 1ull))] = k;
  }
  __syncthreads();

  // bitonic sort 512 ascending
  for (int kk = 2; kk <= K_TOP; kk <<= 1) {
    for (int j = kk >> 1; j > 0; j >>= 1) {
      int ixj = tid ^ j;
      if (ixj > tid) {
        bool up = ((tid & kk) == 0);
        unsigned long long A = skey[tid], B = skey[ixj];
        if ((A > B) == up) { skey[tid] = B; skey[ixj] = A; }
      }
      __syncthreads();
    }
  }

  // epilogue: decode the 512 selected boxes to ws
  {
    unsigned long long key = skey[tid];
    const float *boxp, *ancp;
    switch (l) {
      case 0:  boxp = box0; ancp = anc0; break;
      case 1:  boxp = box1; ancp = anc1; break;
      case 2:  boxp = box2; ancp = anc2; break;
      default: boxp = box3; ancp = anc3; break;
    }
    LvlC L = LVL[l];
    float imgf = (float)(*imgp);
    int idx = (int)((key >> 16) & 0xFFFFull);
    unsigned descu = (unsigned)(key >> 32);
    unsigned ascu  = ~descu;
    unsigned u = (ascu & 0x80000000u) ? (ascu & 0x7FFFFFFFu) : ~ascu;
    float x0, y0, x1, y1;
    decode_box(L, boxp, ancp, b, idx, imgf, x0, y0, x1, y1);
    int o = seg * K_TOP + tid;
    float4 bb; bb.x = x0; bb.y = y0; bb.z = x1; bb.w = y1;
    reinterpret_cast<float4*>(boxesWS)[o] = bb;
    scoresWS[o] = __uint_as_float(u);
    labelsWS[o] = (int)((key >> 8) & 0xFFull);
    validWS[o]  = (unsigned)(key & 1ull);
  }
}

// ---------------- Kernel 5: pairwise IoU>T suppression bitmasks (massively parallel) ----------------
__global__ __launch_bounds__(256) void mask_kernel(
    const float* __restrict__ boxesWS, unsigned long long* __restrict__ masks)
{
#pragma clang fp contract(off)
  int blk = (int)blockIdx.x;          // 512 blocks; 32 per segment
  int seg = blk >> 5;
  int wid = (int)threadIdx.x >> 6;    // 4 waves
  int lane = (int)threadIdx.x & 63;
  int waveInSeg = (blk & 31) * 4 + wid;   // 0..127, 4 rows each
  const float4* bb = reinterpret_cast<const float4*>(boxesWS) + seg * K_TOP;

  float4 bj[8]; float aj[8];
#pragma unroll
  for (int c = 0; c < 8; ++c) {
    bj[c] = bb[c * 64 + lane];
    aj[c] = (bj[c].z - bj[c].x) * (bj[c].w - bj[c].y);
  }
#pragma unroll
  for (int rr = 0; rr < 4; ++rr) {
    int r = waveInSeg * 4 + rr;
    float4 br = bb[r];
    float ar_ = (br.z - br.x) * (br.w - br.y);
    unsigned long long* mrow = masks + ((size_t)seg * K_TOP + r) * 8;
#pragma unroll
    for (int c = 0; c < 8; ++c) {
      float ltx = fmaxf(br.x, bj[c].x), lty = fmaxf(br.y, bj[c].y);
      float rbx = fminf(br.z, bj[c].z), rby = fminf(br.w, bj[c].w);
      float ww = fmaxf(rbx - ltx, 0.f), hh = fmaxf(rby - lty, 0.f);
      float inter = ww * hh;
      float iou = inter / (ar_ + aj[c] - inter + 1e-9f);
      unsigned long long bal = __ballot(iou > 0.5f);
      if (lane == 0) mrow[c] = bal;
    }
  }
}

// ---------------- Kernel 6: serial greedy scan (register-pipelined) + output write ----------------
__global__ __launch_bounds__(512) void scan_kernel(
    const unsigned long long* __restrict__ masks,
    const float* __restrict__ boxesWS, const float* __restrict__ scoresWS,
    const int* __restrict__ labelsWS, const unsigned* __restrict__ validWS,
    float* __restrict__ out)
{
  __shared__ unsigned long long sMask[K_TOP * 8];
  __shared__ unsigned sValid[K_TOP];
  __shared__ unsigned long long keepWords[8];

  int seg = (int)blockIdx.x;
  int tid = (int)threadIdx.x;
  const unsigned long long* mp = masks + (size_t)seg * K_TOP * 8;
#pragma unroll
  for (int k2 = 0; k2 < 8; ++k2) sMask[tid * 8 + k2] = mp[tid * 8 + k2];
  sValid[tid] = validWS[seg * K_TOP + tid];
  __syncthreads();

  if (tid < 8) {
    // lanes 0..7 each own one 64-bit word column; rows double-buffered in registers
    unsigned long long rA[8], rB[8];
    unsigned vA[8], vB[8];
#pragma unroll
    for (int j = 0; j < 8; ++j) { rA[j] = sMask[j * 8 + tid]; vA[j] = sValid[j]; }
    unsigned long long kept = 0ull;
    for (int t = 0; t < 64; ++t) {
      if (t + 1 < 64) {
        int nb = (t + 1) * 8;
#pragma unroll
        for (int j = 0; j < 8; ++j) { rB[j] = sMask[(nb + j) * 8 + tid]; vB[j] = sValid[nb + j]; }
      }
#pragma unroll
      for (int j = 0; j < 8; ++j) {
        int i = t * 8 + j;
        unsigned long long confl = __ballot((rA[j] & kept) != 0ull);
        bool ok = (vA[j] != 0u) && (confl == 0ull);
        if (ok && tid == (i >> 6)) kept |= 1ull << (i & 63);
      }
#pragma unroll
      for (int j = 0; j < 8; ++j) { rA[j] = rB[j]; vA[j] = vB[j]; }
    }
    keepWords[tid] = kept;
  }
  __syncthreads();

  int o = seg * K_TOP + tid;
  bool keep = (keepWords[tid >> 6] >> (tid & 63)) & 1ull;
  float4 bx = reinterpret_cast<const float4*>(boxesWS)[o];
  float4 ob;
  ob.x = keep ? bx.x : 0.f;
  ob.y = keep ? bx.y : 0.f;
  ob.z = keep ? bx.z : 0.f;
  ob.w = keep ? bx.w : 0.f;
  reinterpret_cast<float4*>(out)[o] = ob;                   // boxes:  [0,      32768)
  out[32768 + o] = keep ? scoresWS[o] : 0.f;                // scores: [32768,  40960)
  out[40960 + o] = keep ? (float)(labelsWS[o] + 1) : 0.f;   // labels: [40960,  49152)
  out[49152 + o] = keep ? 1.f : 0.f;                        // keep:   [49152,  57344)
}

extern "C" void kernel_launch(void* const* d_in, const int* in_sizes, int n_in,
                              void* d_out, int out_size, void* d_ws, size_t ws_size,
                              hipStream_t stream)
{
  const float* cls0 = (const float*)d_in[0];
  const float* box0 = (const float*)d_in[1];
  const float* anc0 = (const float*)d_in[2];
  const float* cls1 = (const float*)d_in[3];
  const float* box1 = (const float*)d_in[4];
  const float* anc1 = (const float*)d_in[5];
  const float* cls2 = (const float*)d_in[6];
  const float* box2 = (const float*)d_in[7];
  const float* anc2 = (const float*)d_in[8];
  const float* cls3 = (const float*)d_in[9];
  const float* box3 = (const float*)d_in[10];
  const float* anc3 = (const float*)d_in[11];
  const int*   imgp = (const int*)d_in[12];

  // ws layout (bytes):
  char* ws = (char*)d_ws;
  unsigned long long* keys    = (unsigned long long*)(ws + 0);         // 2,088,960
  unsigned long long* masks   = (unsigned long long*)(ws + 2088960);   // 524,288
  float*              boxesWS = (float*)(ws + 2613248);                // 131,072
  float*              scoresWS= (float*)(ws + 2744320);                // 32,768
  int*                labelsWS= (int*)(ws + 2777088);                  // 32,768
  unsigned*           validWS = (unsigned*)(ws + 2809856);             // 32,768
  unsigned*           ghist   = (unsigned*)(ws + 2842624);             // 262,144
  unsigned*           segInfo = (unsigned*)(ws + 3104768);             // 128
  unsigned*           candCnt = (unsigned*)(ws + 3104896);             // 2,048 (16 x 128B padded)
  unsigned long long* cand    = (unsigned long long*)(ws + 3106944);   // 655,360
  float* out = (float*)d_out;

  // zero ghist + segInfo + candCnt in one contiguous memset
  hipMemsetAsync(ghist, 0, 262144 + 128 + 2048, stream);

  decode_kernel<<<1020, 256, 0, stream>>>(cls0, box0, anc0, cls1, box1, anc1,
                                          cls2, box2, anc2, cls3, box3, anc3,
                                          imgp, keys, ghist);
  thresh_kernel<<<16, 1024, 0, stream>>>(ghist, segInfo);
  compact_kernel<<<1020, 256, 0, stream>>>(keys, segInfo, cand, candCnt);
  final_kernel<<<16, 512, 0, stream>>>(keys, cand, candCnt, segInfo,
                                       box0, anc0, box1, anc1, box2, anc2, box3, anc3,
                                       imgp, boxesWS, scoresWS, labelsWS, validWS);
  mask_kernel<<<512, 256, 0, stream>>>(boxesWS, masks);
  scan_kernel<<<16, 512, 0, stream>>>(masks, boxesWS, scoresWS, labelsWS, validWS, out);
}